// Round 11
// baseline (126.418 us; speedup 1.0000x reference)
//
#include <hip/hip_runtime.h>

// PiecewisePolynomial: out[b,o] = sum_i sum_j L_j(x_in(b,i)) * w[o, i, 3*seg(b,i)+j]
// B=512, IN_F=256, OUT_F=256, SEGMENTS=16, N=4 (nodes -1,-0.5,0.5,1)
//
// R11: ZERO-LDS ZERO-BARRIER consumer. pp_prep builds
//   wp[i][s][o] : uint2 = 4 packed f16 weights {(w[3s],w[3s+1]),(w[3s+2],w[3s+3])}
//   bt[b][i]    : uint4 = {cA f16x2, cB f16x2, seg, 0}
// pp_main: one wave per (b, o-tile-of-64); per (b,i): uniform bt entry via
// scalar pipe + ONE lane-contiguous global_load_dwordx2 from L2 + 2 fdot2.
// No __shared__, no __syncthreads, fully independent waves.

typedef _Float16 h2 __attribute__((ext_vector_type(2)));

#define OSTRIDE 12544                  // 256*49
#define WP_U2   (256 * 16 * 256)       // uint2 count = 8.4 MB

// ---- prep ----
// blocks 0..255 (i=blk, thread=o): pack w[o][i][*] -> wp[i][s][o] (coalesced o-writes)
// blocks 256..383: bt[b][i] = {cA,cB,seg,0}, 1024 entries per block
__global__ __launch_bounds__(256)
void pp_prep(const float* __restrict__ x, const float* __restrict__ w,
             uint2* __restrict__ wp, uint4* __restrict__ bt) {
    const int t = threadIdx.x;
    const int blk = blockIdx.x;
    if (blk < 256) {
        const int i = blk, o = t;
        const float* src = w + (size_t)o * OSTRIDE + i * 49;
        float v[49];
        #pragma unroll
        for (int k = 0; k < 49; ++k) v[k] = src[k];
        #pragma unroll
        for (int s = 0; s < 16; ++s) {
            auto p0 = __builtin_amdgcn_cvt_pkrtz(v[3*s],   v[3*s+1]);
            auto p1 = __builtin_amdgcn_cvt_pkrtz(v[3*s+2], v[3*s+3]);
            uint2 u;
            u.x = __builtin_bit_cast(unsigned int, p0);
            u.y = __builtin_bit_cast(unsigned int, p1);
            wp[((size_t)i * 16 + s) * 256 + o] = u;      // lane=o contiguous
        }
    } else {
        const int e = (blk - 256) * 1024 + t * 4;        // flat (b*256 + i)
        float4 xv = *(const float4*)(x + e);
        const float xs[4] = {xv.x, xv.y, xv.z, xv.w};
        #pragma unroll
        for (int q = 0; q < 4; ++q) {
            float xx = xs[q];
            int id = (int)((xx + 1.0f) * 8.0f);
            id = id < 0 ? 0 : (id > 15 ? 15 : id);
            float u = (xx - ((float)id * 0.125f - 1.0f)) * 16.0f - 1.0f;
            float a = u + 1.0f, b2 = u + 0.5f, cc = u - 0.5f, d = u - 1.0f;
            float c0 = b2 * cc * d  * (-2.0f / 3.0f);
            float c1 = a  * cc * d  * ( 4.0f / 3.0f);
            float c2 = a  * b2 * d  * (-4.0f / 3.0f);
            float c3 = a  * b2 * cc * ( 2.0f / 3.0f);
            auto pA = __builtin_amdgcn_cvt_pkrtz(c0, c1);
            auto pB = __builtin_amdgcn_cvt_pkrtz(c2, c3);
            uint4 v;
            v.x = __builtin_bit_cast(unsigned int, pA);
            v.y = __builtin_bit_cast(unsigned int, pB);
            v.z = (unsigned int)id;
            v.w = 0u;
            bt[e + q] = v;
        }
    }
}

// ---- main: grid (4 otile, 512 b) x 64 threads (one wave), no LDS/barriers ----
__global__ __launch_bounds__(64)
void pp_main(const uint2* __restrict__ wp, const uint4* __restrict__ bt,
             float* __restrict__ out) {
    const int lane = threadIdx.x;
    const int o    = blockIdx.x * 64 + lane;
    const int b    = blockIdx.y;
    const uint4* btb = bt + (size_t)b * 256;

    float acc = 0.0f;
    #pragma unroll 8
    for (int i = 0; i < 256; ++i) {
        const uint4 B = btb[i];                      // uniform addr -> scalar pipe
        const uint2 wv = wp[((size_t)(i * 16 + (int)B.z)) * 256 + o];  // 512B/wave, L2
        acc = __builtin_amdgcn_fdot2(__builtin_bit_cast(h2, wv.x),
                                     __builtin_bit_cast(h2, B.x), acc, false);
        acc = __builtin_amdgcn_fdot2(__builtin_bit_cast(h2, wv.y),
                                     __builtin_bit_cast(h2, B.y), acc, false);
    }
    out[(size_t)b * 256 + o] = acc;                  // 256B/wave contiguous
}

extern "C" void kernel_launch(void* const* d_in, const int* in_sizes, int n_in,
                              void* d_out, int out_size, void* d_ws, size_t ws_size,
                              hipStream_t stream) {
    const float* x = (const float*)d_in[0];
    const float* w = (const float*)d_in[1];
    float* out = (float*)d_out;
    uint2* wp = (uint2*)d_ws;                                  // 8.4 MB
    uint4* bt = (uint4*)((char*)d_ws + (size_t)WP_U2 * 8);     // 2 MB
    (void)ws_size; (void)n_in; (void)in_sizes; (void)out_size;

    pp_prep<<<dim3(384), 256, 0, stream>>>(x, w, wp, bt);
    pp_main<<<dim3(4, 512), 64, 0, stream>>>(wp, bt, out);
}